// Round 1
// baseline (385.948 us; speedup 1.0000x reference)
//
#include <hip/hip_runtime.h>
#include <hip/hip_bf16.h>

#define NEG_SLOPE 0.2f

// ---------------- projection: ft = feat @ fc_w  (N x 128) ----------------
// block = 256 threads, 16 nodes per block; feat tile staged in LDS.
__global__ __launch_bounds__(256) void k_proj(const float* __restrict__ feat,
                                              const float* __restrict__ fc_w,
                                              float* __restrict__ ft, int N) {
    __shared__ float fl[16 * 128];
    int t = threadIdx.x;
    int n0 = blockIdx.x * 16;
#pragma unroll
    for (int j = 0; j < 8; ++j) {
        int idx = j * 256 + t;
        int r = idx >> 7, c = idx & 127;
        int n = n0 + r;
        fl[idx] = (n < N) ? feat[(size_t)n * 128 + c] : 0.f;
    }
    __syncthreads();

    int c = t & 127;
    int rh = t >> 7;  // 0 or 1: which 8-node half this thread covers
    float acc[8];
#pragma unroll
    for (int j = 0; j < 8; ++j) acc[j] = 0.f;

    const float* fbase = fl + rh * 8 * 128;
    for (int k = 0; k < 128; k += 4) {
        float w0 = fc_w[(size_t)(k + 0) * 128 + c];
        float w1 = fc_w[(size_t)(k + 1) * 128 + c];
        float w2 = fc_w[(size_t)(k + 2) * 128 + c];
        float w3 = fc_w[(size_t)(k + 3) * 128 + c];
#pragma unroll
        for (int j = 0; j < 8; ++j) {
            float4 f = *(const float4*)(fbase + j * 128 + k);
            acc[j] = fmaf(f.x, w0, acc[j]);
            acc[j] = fmaf(f.y, w1, acc[j]);
            acc[j] = fmaf(f.z, w2, acc[j]);
            acc[j] = fmaf(f.w, w3, acc[j]);
        }
    }
#pragma unroll
    for (int j = 0; j < 8; ++j) {
        int n = n0 + rh * 8 + j;
        if (n < N) ft[(size_t)n * 128 + c] = acc[j];
    }
}

// ---------------- el/er: per (node, head) dot with attn vectors ----------
__global__ void k_elr(const float* __restrict__ ft, const float* __restrict__ attn_l,
                      const float* __restrict__ attn_r, float* __restrict__ el,
                      float* __restrict__ er, int N) {
    int t = blockIdx.x * blockDim.x + threadIdx.x;
    if (t >= N * 4) return;
    int n = t >> 2, h = t & 3;
    const float4* f4 = (const float4*)(ft + (size_t)n * 128 + h * 32);
    const float4* al4 = (const float4*)(attn_l + h * 32);
    const float4* ar4 = (const float4*)(attn_r + h * 32);
    float sl = 0.f, sr = 0.f;
#pragma unroll
    for (int j = 0; j < 8; ++j) {
        float4 f = f4[j], a = al4[j], b = ar4[j];
        sl += f.x * a.x + f.y * a.y + f.z * a.z + f.w * a.w;
        sr += f.x * b.x + f.y * b.y + f.z * b.z + f.w * b.w;
    }
    el[t] = sl;
    er[t] = sr;
}

// ---------------- counting sort: histogram over dst ----------------------
__global__ void k_hist(const int* __restrict__ dst, int* __restrict__ cnt, int E) {
    int e = blockIdx.x * blockDim.x + threadIdx.x;
    if (e < E) atomicAdd(&cnt[dst[e]], 1);
}

// ---------------- exclusive scan over 50000 counts (one block) -----------
__global__ __launch_bounds__(1024) void k_scan(const int* __restrict__ cnt,
                                               int* __restrict__ row_off,
                                               int* __restrict__ cursor, int N) {
    __shared__ int buf[1024];
    __shared__ int carry;
    int t = threadIdx.x;
    if (t == 0) carry = 0;
    __syncthreads();
    for (int base = 0; base < N; base += 1024) {
        int i = base + t;
        int v = (i < N) ? cnt[i] : 0;
        buf[t] = v;
        __syncthreads();
        for (int off = 1; off < 1024; off <<= 1) {
            int add = (t >= off) ? buf[t - off] : 0;
            __syncthreads();
            buf[t] += add;
            __syncthreads();
        }
        int incl = buf[t];
        int excl = incl - v;
        if (i < N) {
            int ro = carry + excl;
            row_off[i] = ro;
            cursor[i] = ro;
        }
        __syncthreads();
        if (t == 1023) carry += incl;
        __syncthreads();
    }
    if (t == 0) row_off[N] = carry;
}

// ---------------- scatter edge ids into CSR order ------------------------
__global__ void k_scatter(const int* __restrict__ src, const int* __restrict__ dst,
                          int* __restrict__ cursor, int* __restrict__ src_sorted, int E) {
    int e = blockIdx.x * blockDim.x + threadIdx.x;
    if (e < E) {
        int d = dst[e];
        int pos = atomicAdd(&cursor[d], 1);
        src_sorted[pos] = src[e];
    }
}

// ---------------- gather-form softmax + aggregation: one wave per node ---
__global__ __launch_bounds__(256) void k_agg(
    const float* __restrict__ ft, const float* __restrict__ y,
    const float* __restrict__ el, const float* __restrict__ er,
    const float* __restrict__ bias, const int* __restrict__ row_off,
    const int* __restrict__ src_sorted, float* __restrict__ rst,
    float* __restrict__ yp, int N) {
    int w = (int)((blockIdx.x * (size_t)blockDim.x + threadIdx.x) >> 6);
    int lane = threadIdx.x & 63;
    if (w >= N) return;

    int beg = row_off[w], end = row_off[w + 1];
    float4 er4 = *(const float4*)(er + (size_t)w * 4);

    // pass A: s = sum(exp(e)) per head (no max-subtraction; e is bounded)
    float4 s4 = make_float4(0.f, 0.f, 0.f, 0.f);
    for (int i = beg + lane; i < end; i += 64) {
        int s = src_sorted[i];
        float4 el4 = *(const float4*)(el + (size_t)s * 4);
        float ex = el4.x + er4.x; ex = ex > 0.f ? ex : NEG_SLOPE * ex;
        float ey = el4.y + er4.y; ey = ey > 0.f ? ey : NEG_SLOPE * ey;
        float ez = el4.z + er4.z; ez = ez > 0.f ? ez : NEG_SLOPE * ez;
        float ew = el4.w + er4.w; ew = ew > 0.f ? ew : NEG_SLOPE * ew;
        s4.x += __expf(ex);
        s4.y += __expf(ey);
        s4.z += __expf(ez);
        s4.w += __expf(ew);
    }
#pragma unroll
    for (int off = 32; off; off >>= 1) {
        s4.x += __shfl_xor(s4.x, off);
        s4.y += __shfl_xor(s4.y, off);
        s4.z += __shfl_xor(s4.z, off);
        s4.w += __shfl_xor(s4.w, off);
    }
    float4 inv4;
    inv4.x = 1.f / fmaxf(s4.x, 1e-9f);
    inv4.y = 1.f / fmaxf(s4.y, 1e-9f);
    inv4.z = 1.f / fmaxf(s4.z, 1e-9f);
    inv4.w = 1.f / fmaxf(s4.w, 1e-9f);

    // pass B: whole wave cooperates per edge
    float acc0 = 0.f, acc1 = 0.f, accy = 0.f;
    for (int i = beg; i < end; ++i) {
        int s = src_sorted[i];  // wave-uniform broadcast load
        float4 el4 = *(const float4*)(el + (size_t)s * 4);
        float ex = el4.x + er4.x; ex = ex > 0.f ? ex : NEG_SLOPE * ex;
        float ey = el4.y + er4.y; ey = ey > 0.f ? ey : NEG_SLOPE * ey;
        float ez = el4.z + er4.z; ez = ez > 0.f ? ez : NEG_SLOPE * ez;
        float ew = el4.w + er4.w; ew = ew > 0.f ? ew : NEG_SLOPE * ew;
        float ax = __expf(ex) * inv4.x;
        float ay_ = __expf(ey) * inv4.y;
        float az = __expf(ez) * inv4.z;
        float aw = __expf(ew) * inv4.w;

        const float* fts = ft + (size_t)s * 128;
        float f0 = fts[lane];
        float f1 = fts[lane + 64];
        float yv = y[(size_t)s * 16 + (lane & 15)];

        float a01 = (lane & 32) ? ay_ : ax;          // heads 0..1 for lanes 0..63
        float a23 = (lane & 32) ? aw : az;           // heads 2..3 for lanes 0..63 (+64 cols)
        float ayv = (lane & 32) ? ((lane & 16) ? aw : az)
                                : ((lane & 16) ? ay_ : ax);  // head = lane>>4

        acc0 = fmaf(f0, a01, acc0);
        acc1 = fmaf(f1, a23, acc1);
        accy = fmaf(yv, ayv, accy);
    }

    rst[(size_t)w * 128 + lane] = acc0 + bias[lane];
    rst[(size_t)w * 128 + 64 + lane] = acc1 + bias[64 + lane];
    yp[(size_t)w * 64 + lane] = accy;
}

extern "C" void kernel_launch(void* const* d_in, const int* in_sizes, int n_in,
                              void* d_out, int out_size, void* d_ws, size_t ws_size,
                              hipStream_t stream) {
    const float* feat   = (const float*)d_in[0];
    const float* y      = (const float*)d_in[1];
    const float* fc_w   = (const float*)d_in[2];
    const float* attn_l = (const float*)d_in[3];
    const float* attn_r = (const float*)d_in[4];
    const float* bias   = (const float*)d_in[5];
    const int*   src    = (const int*)d_in[6];
    const int*   dst    = (const int*)d_in[7];

    const int N = in_sizes[0] / 128;  // FIN = 128
    const int E = in_sizes[6];

    // workspace layout (all 16B-aligned given f32 counts used)
    float* ft = (float*)d_ws;                       // N*128
    float* el = ft + (size_t)N * 128;               // N*4
    float* er = el + (size_t)N * 4;                 // N*4
    int* cnt = (int*)(er + (size_t)N * 4);          // N
    int* row_off = cnt + N;                         // N+1
    int* cursor = row_off + (N + 1);                // N
    int* src_sorted = cursor + N;                   // E

    float* rst = (float*)d_out;                     // N*128
    float* yp = rst + (size_t)N * 128;              // N*64

    hipMemsetAsync(cnt, 0, (size_t)N * sizeof(int), stream);

    dim3 blk(256);
    k_proj<<<dim3((N + 15) / 16), blk, 0, stream>>>(feat, fc_w, ft, N);
    k_elr<<<dim3((N * 4 + 255) / 256), blk, 0, stream>>>(ft, attn_l, attn_r, el, er, N);
    k_hist<<<dim3((E + 255) / 256), blk, 0, stream>>>(dst, cnt, E);
    k_scan<<<dim3(1), dim3(1024), 0, stream>>>(cnt, row_off, cursor, N);
    k_scatter<<<dim3((E + 255) / 256), blk, 0, stream>>>(src, dst, cursor, src_sorted, E);
    k_agg<<<dim3(((size_t)N * 64 + 255) / 256), blk, 0, stream>>>(
        ft, y, el, er, bias, row_off, src_sorted, rst, yp, N);
}

// Round 2
// 372.676 us; speedup vs baseline: 1.0356x; 1.0356x over previous
//
#include <hip/hip_runtime.h>
#include <hip/hip_bf16.h>

#define NEG_SLOPE 0.2f

// ---------------- fused1: projection (blocks < projB) + dst histogram ----
// proj: block = 256 thr, 16 nodes; thread owns cols (c, c+64) for 4 nodes.
__global__ __launch_bounds__(256) void k_fused1(
    const float* __restrict__ feat, const float* __restrict__ fc_w,
    float* __restrict__ ft, const int* __restrict__ dst, int* __restrict__ cnt,
    int N, int E, int projB, int histThreads) {
    __shared__ float fl[16 * 128];
    int t = threadIdx.x;
    if ((int)blockIdx.x < projB) {
        int n0 = blockIdx.x * 16;
#pragma unroll
        for (int j = 0; j < 8; ++j) {
            int idx = j * 256 + t;
            int r = idx >> 7, c = idx & 127;
            int n = n0 + r;
            fl[idx] = (n < N) ? feat[(size_t)n * 128 + c] : 0.f;
        }
        __syncthreads();

        int c = t & 63;   // cols c and c+64
        int g = t >> 6;   // node group: nodes n0+4g .. n0+4g+3
        float acc[4][2];
#pragma unroll
        for (int j = 0; j < 4; ++j) acc[j][0] = acc[j][1] = 0.f;

        const float* fb = fl + g * 4 * 128;
        for (int k = 0; k < 128; k += 4) {
            float wa0 = fc_w[(size_t)(k + 0) * 128 + c];
            float wb0 = fc_w[(size_t)(k + 0) * 128 + c + 64];
            float wa1 = fc_w[(size_t)(k + 1) * 128 + c];
            float wb1 = fc_w[(size_t)(k + 1) * 128 + c + 64];
            float wa2 = fc_w[(size_t)(k + 2) * 128 + c];
            float wb2 = fc_w[(size_t)(k + 2) * 128 + c + 64];
            float wa3 = fc_w[(size_t)(k + 3) * 128 + c];
            float wb3 = fc_w[(size_t)(k + 3) * 128 + c + 64];
#pragma unroll
            for (int j = 0; j < 4; ++j) {
                float4 f = *(const float4*)(fb + j * 128 + k);
                acc[j][0] = fmaf(f.x, wa0, acc[j][0]);
                acc[j][1] = fmaf(f.x, wb0, acc[j][1]);
                acc[j][0] = fmaf(f.y, wa1, acc[j][0]);
                acc[j][1] = fmaf(f.y, wb1, acc[j][1]);
                acc[j][0] = fmaf(f.z, wa2, acc[j][0]);
                acc[j][1] = fmaf(f.z, wb2, acc[j][1]);
                acc[j][0] = fmaf(f.w, wa3, acc[j][0]);
                acc[j][1] = fmaf(f.w, wb3, acc[j][1]);
            }
        }
#pragma unroll
        for (int j = 0; j < 4; ++j) {
            int n = n0 + g * 4 + j;
            if (n < N) {
                ft[(size_t)n * 128 + c] = acc[j][0];
                ft[(size_t)n * 128 + c + 64] = acc[j][1];
            }
        }
    } else {
        int tid = (blockIdx.x - projB) * 256 + t;
        for (int e = tid; e < E; e += histThreads) atomicAdd(&cnt[dst[e]], 1);
    }
}

// ---------------- scan: chunk-sum + block scan + chunk writeback ---------
__global__ __launch_bounds__(1024) void k_scan(const int* __restrict__ cnt,
                                               int* __restrict__ row_off,
                                               int* __restrict__ cursor, int N) {
    const int T = 1024;
    int t = threadIdx.x;
    int chunk = (N + T - 1) / T;
    int b = t * chunk;
    int e = min(N, b + chunk);
    int s = 0;
    for (int i = b; i < e; ++i) s += cnt[i];

    __shared__ int wsum[16];
    int lane = t & 63, w = t >> 6;
    int v = s;
#pragma unroll
    for (int off = 1; off < 64; off <<= 1) {
        int u = __shfl_up(v, off);
        if (lane >= off) v += u;
    }
    if (lane == 63) wsum[w] = v;
    __syncthreads();
    if (w == 0) {
        int x = (lane < 16) ? wsum[lane] : 0;
#pragma unroll
        for (int off = 1; off < 16; off <<= 1) {
            int u = __shfl_up(x, off);
            if (lane >= off) x += u;
        }
        if (lane < 16) wsum[lane] = x;
    }
    __syncthreads();
    int excl = v - s + ((w > 0) ? wsum[w - 1] : 0);

    int run = excl;
    for (int i = b; i < e; ++i) {
        row_off[i] = run;
        cursor[i] = run;
        run += cnt[i];
    }
    if (t == T - 1) row_off[N] = run;
}

// ---------------- fused2: el/er dots (blocks < elrB) + CSR scatter -------
__global__ __launch_bounds__(256) void k_fused2(
    const float* __restrict__ ft, const float* __restrict__ attn_l,
    const float* __restrict__ attn_r, float* __restrict__ el, float* __restrict__ er,
    const int* __restrict__ src, const int* __restrict__ dst,
    int* __restrict__ cursor, int* __restrict__ src_sorted,
    int N, int E, int elrB, int scatThreads) {
    int t = threadIdx.x;
    if ((int)blockIdx.x < elrB) {
        int id = blockIdx.x * 256 + t;
        if (id >= N * 4) return;
        int n = id >> 2, h = id & 3;
        const float4* f4 = (const float4*)(ft + (size_t)n * 128 + h * 32);
        const float4* al4 = (const float4*)(attn_l + h * 32);
        const float4* ar4 = (const float4*)(attn_r + h * 32);
        float sl = 0.f, sr = 0.f;
#pragma unroll
        for (int j = 0; j < 8; ++j) {
            float4 f = f4[j], a = al4[j], b = ar4[j];
            sl += f.x * a.x + f.y * a.y + f.z * a.z + f.w * a.w;
            sr += f.x * b.x + f.y * b.y + f.z * b.z + f.w * b.w;
        }
        el[id] = sl;
        er[id] = sr;
    } else {
        int tid = (blockIdx.x - elrB) * 256 + t;
        for (int e = tid; e < E; e += scatThreads) {
            int d = dst[e];
            int pos = atomicAdd(&cursor[d], 1);
            src_sorted[pos] = src[e];
        }
    }
}

// ---------------- single-pass gather aggregation: one wave per node ------
// lanes 0..31: feature quad 4l (head = l>>3); lanes 32..63: y quad (dup 48+)
__global__ __launch_bounds__(256) void k_agg(
    const float* __restrict__ ft, const float* __restrict__ y,
    const float* __restrict__ el, const float* __restrict__ er,
    const float* __restrict__ bias, const int* __restrict__ row_off,
    const int* __restrict__ src_sorted, float* __restrict__ rst,
    float* __restrict__ yp, int N) {
    int w = (int)((blockIdx.x * (size_t)blockDim.x + threadIdx.x) >> 6);
    int lane = threadIdx.x & 63;
    if (w >= N) return;

    bool is_ft = lane < 32;
    int k = (lane - 32) & 15;                     // y-lane slot
    int head = is_ft ? (lane >> 3) : (k >> 2);
    int shift = is_ft ? 7 : 4;                    // row stride in elements
    const float* base_l = (is_ft ? ft : y) + (is_ft ? 4 * lane : 4 * (k & 3));

    float er_l = er[(size_t)w * 4 + head];

    int beg = row_off[w], end = row_off[w + 1];
    float4 acc = make_float4(0.f, 0.f, 0.f, 0.f);
    float ssum = 0.f;

    int i = beg;
    if (i < end) {
        int s = src_sorted[i];
        float elv = el[(size_t)s * 4 + head];
        float4 v = *(const float4*)(base_l + ((size_t)s << shift));
        for (++i; i < end; ++i) {
            int s2 = src_sorted[i];                                   // prefetch
            float elv2 = el[(size_t)s2 * 4 + head];
            float4 v2 = *(const float4*)(base_l + ((size_t)s2 << shift));
            float e = elv + er_l;
            e = fmaxf(e, NEG_SLOPE * e);                              // leaky_relu
            float ee = __expf(e);
            ssum += ee;
            acc.x = fmaf(ee, v.x, acc.x);
            acc.y = fmaf(ee, v.y, acc.y);
            acc.z = fmaf(ee, v.z, acc.z);
            acc.w = fmaf(ee, v.w, acc.w);
            elv = elv2;
            v = v2;
        }
        float e = elv + er_l;
        e = fmaxf(e, NEG_SLOPE * e);
        float ee = __expf(e);
        ssum += ee;
        acc.x = fmaf(ee, v.x, acc.x);
        acc.y = fmaf(ee, v.y, acc.y);
        acc.z = fmaf(ee, v.z, acc.z);
        acc.w = fmaf(ee, v.w, acc.w);
    }

    float inv = 1.f / fmaxf(ssum, 1e-9f);
    acc.x *= inv; acc.y *= inv; acc.z *= inv; acc.w *= inv;

    if (is_ft) {
        float4 b4 = *(const float4*)(bias + 4 * lane);
        acc.x += b4.x; acc.y += b4.y; acc.z += b4.z; acc.w += b4.w;
        *(float4*)(rst + (size_t)w * 128 + 4 * lane) = acc;
    } else if (lane < 48) {
        *(float4*)(yp + (size_t)w * 64 + 4 * k) = acc;
    }
}

extern "C" void kernel_launch(void* const* d_in, const int* in_sizes, int n_in,
                              void* d_out, int out_size, void* d_ws, size_t ws_size,
                              hipStream_t stream) {
    const float* feat   = (const float*)d_in[0];
    const float* y      = (const float*)d_in[1];
    const float* fc_w   = (const float*)d_in[2];
    const float* attn_l = (const float*)d_in[3];
    const float* attn_r = (const float*)d_in[4];
    const float* bias   = (const float*)d_in[5];
    const int*   src    = (const int*)d_in[6];
    const int*   dst    = (const int*)d_in[7];

    const int N = in_sizes[0] / 128;  // FIN = 128
    const int E = in_sizes[6];

    float* ft = (float*)d_ws;                       // N*128
    float* el = ft + (size_t)N * 128;               // N*4
    float* er = el + (size_t)N * 4;                 // N*4
    int* cnt = (int*)(er + (size_t)N * 4);          // N
    int* row_off = cnt + N;                         // N+1
    int* cursor = row_off + (N + 1);                // N
    int* src_sorted = cursor + N;                   // E

    float* rst = (float*)d_out;                     // N*128
    float* yp = rst + (size_t)N * 128;              // N*64

    hipMemsetAsync(cnt, 0, (size_t)N * sizeof(int), stream);

    const int projB = (N + 15) / 16;
    const int histB = 1024;
    const int elrB = (N * 4 + 255) / 256;
    const int scatB = 1024;

    k_fused1<<<dim3(projB + histB), dim3(256), 0, stream>>>(
        feat, fc_w, ft, dst, cnt, N, E, projB, histB * 256);
    k_scan<<<dim3(1), dim3(1024), 0, stream>>>(cnt, row_off, cursor, N);
    k_fused2<<<dim3(elrB + scatB), dim3(256), 0, stream>>>(
        ft, attn_l, attn_r, el, er, src, dst, cursor, src_sorted, N, E, elrB, scatB * 256);
    k_agg<<<dim3(((size_t)N * 64 + 255) / 256), dim3(256), 0, stream>>>(
        ft, y, el, er, bias, row_off, src_sorted, rst, yp, N);
}

// Round 4
// 362.227 us; speedup vs baseline: 1.0655x; 1.0288x over previous
//
#include <hip/hip_runtime.h>
#include <hip/hip_bf16.h>

#define NEG_SLOPE 0.2f
#define ROWB 320  // bytes per combined node row: ft bf16[128] | y bf16[16] | el f32[4] | er f32[4]

typedef unsigned short u16;
typedef unsigned int u32;

__device__ __forceinline__ u16 f32_to_bf16(float x) {
    u32 u = __float_as_uint(x);
    u32 r = u + 0x7fffu + ((u >> 16) & 1u);  // round-to-nearest-even
    return (u16)(r >> 16);
}

// ---------------- k1: projection + el/er + bf16 pack + y cast (+ hist) ----
// proj blocks: 256 thr, 16 nodes; thread owns cols (c, c+64) for 4 nodes.
__global__ __launch_bounds__(256) void k_proj(
    const float* __restrict__ feat, const float* __restrict__ fc_w,
    const float* __restrict__ y, const float* __restrict__ attn_l,
    const float* __restrict__ attn_r, char* __restrict__ comb,
    const int* __restrict__ dst, int* __restrict__ cnt,
    int N, int E, int projB, int histThreads) {
    __shared__ float fl[16 * 128];
    int t = threadIdx.x;
    if ((int)blockIdx.x >= projB) {
        int tid = (blockIdx.x - projB) * 256 + t;
        for (int e = tid; e < E; e += histThreads) atomicAdd(&cnt[dst[e]], 1);
        return;
    }
    int n0 = blockIdx.x * 16;
#pragma unroll
    for (int j = 0; j < 8; ++j) {
        int idx = j * 256 + t;
        int r = idx >> 7, c = idx & 127;
        int n = n0 + r;
        fl[idx] = (n < N) ? feat[(size_t)n * 128 + c] : 0.f;
    }
    // y cast: 16 nodes x 16 cols
    {
        int jj = t >> 4, col = t & 15;
        int n = n0 + jj;
        if (n < N) {
            float yv = y[(size_t)n * 16 + col];
            *(u16*)(comb + (size_t)n * ROWB + 256 + 2 * col) = f32_to_bf16(yv);
        }
    }
    __syncthreads();

    int c = t & 63;   // cols c and c+64
    int g = t >> 6;   // node group: nodes n0+4g .. n0+4g+3
    float alv0 = attn_l[c], alv1 = attn_l[64 + c];
    float arv0 = attn_r[c], arv1 = attn_r[64 + c];

    float acc[4][2];
#pragma unroll
    for (int j = 0; j < 4; ++j) acc[j][0] = acc[j][1] = 0.f;

    const float* fb = fl + g * 4 * 128;
    for (int k = 0; k < 128; k += 4) {
        float wa0 = fc_w[(size_t)(k + 0) * 128 + c];
        float wb0 = fc_w[(size_t)(k + 0) * 128 + c + 64];
        float wa1 = fc_w[(size_t)(k + 1) * 128 + c];
        float wb1 = fc_w[(size_t)(k + 1) * 128 + c + 64];
        float wa2 = fc_w[(size_t)(k + 2) * 128 + c];
        float wb2 = fc_w[(size_t)(k + 2) * 128 + c + 64];
        float wa3 = fc_w[(size_t)(k + 3) * 128 + c];
        float wb3 = fc_w[(size_t)(k + 3) * 128 + c + 64];
#pragma unroll
        for (int j = 0; j < 4; ++j) {
            float4 f = *(const float4*)(fb + j * 128 + k);
            acc[j][0] = fmaf(f.x, wa0, acc[j][0]);
            acc[j][1] = fmaf(f.x, wb0, acc[j][1]);
            acc[j][0] = fmaf(f.y, wa1, acc[j][0]);
            acc[j][1] = fmaf(f.y, wb1, acc[j][1]);
            acc[j][0] = fmaf(f.z, wa2, acc[j][0]);
            acc[j][1] = fmaf(f.z, wb2, acc[j][1]);
            acc[j][0] = fmaf(f.w, wa3, acc[j][0]);
            acc[j][1] = fmaf(f.w, wb3, acc[j][1]);
        }
    }

#pragma unroll
    for (int j = 0; j < 4; ++j) {
        int n = n0 + g * 4 + j;
        if (n >= N) break;
        char* row = comb + (size_t)n * ROWB;
        // ft bf16 stores: cols c and c+64
        *(u16*)(row + 2 * c) = f32_to_bf16(acc[j][0]);
        *(u16*)(row + 2 * (c + 64)) = f32_to_bf16(acc[j][1]);
        // el/er via 32-lane xor reduction
        float p0 = acc[j][0] * alv0;   // -> el[c>>5]
        float p1 = acc[j][1] * alv1;   // -> el[2 + (c>>5)]
        float q0 = acc[j][0] * arv0;   // -> er[c>>5]
        float q1 = acc[j][1] * arv1;   // -> er[2 + (c>>5)]
#pragma unroll
        for (int off = 1; off < 32; off <<= 1) {
            p0 += __shfl_xor(p0, off);
            p1 += __shfl_xor(p1, off);
            q0 += __shfl_xor(q0, off);
            q1 += __shfl_xor(q1, off);
        }
        float* ep = (float*)(row + 288);
        if (c == 0) { ep[0] = p0; ep[2] = p1; ep[4] = q0; ep[6] = q1; }
        if (c == 32) { ep[1] = p0; ep[3] = p1; ep[5] = q0; ep[7] = q1; }
    }
}

// ---------------- scan: chunk-sum + block scan + chunk writeback ---------
__global__ __launch_bounds__(1024) void k_scan(const int* __restrict__ cnt,
                                               int* __restrict__ row_off,
                                               int* __restrict__ cursor, int N) {
    const int T = 1024;
    int t = threadIdx.x;
    int chunk = (N + T - 1) / T;
    int b = t * chunk;
    int e = min(N, b + chunk);
    int s = 0;
    for (int i = b; i < e; ++i) s += cnt[i];

    __shared__ int wsum[16];
    int lane = t & 63, w = t >> 6;
    int v = s;
#pragma unroll
    for (int off = 1; off < 64; off <<= 1) {
        int u = __shfl_up(v, off);
        if (lane >= off) v += u;
    }
    if (lane == 63) wsum[w] = v;
    __syncthreads();
    if (w == 0) {
        int x = (lane < 16) ? wsum[lane] : 0;
#pragma unroll
        for (int off = 1; off < 16; off <<= 1) {
            int u = __shfl_up(x, off);
            if (lane >= off) x += u;
        }
        if (lane < 16) wsum[lane] = x;
    }
    __syncthreads();
    int excl = v - s + ((w > 0) ? wsum[w - 1] : 0);

    int run = excl;
    for (int i = b; i < e; ++i) {
        row_off[i] = run;
        cursor[i] = run;
        run += cnt[i];
    }
    if (t == T - 1) row_off[N] = run;
}

// ---------------- scatter edge ids (u16) into CSR order ------------------
__global__ void k_scatter(const int* __restrict__ src, const int* __restrict__ dst,
                          int* __restrict__ cursor, u16* __restrict__ src_sorted,
                          int E, int nThreads) {
    int tid = blockIdx.x * blockDim.x + threadIdx.x;
    for (int e = tid; e < E; e += nThreads) {
        int d = dst[e];
        int pos = atomicAdd(&cursor[d], 1);
        src_sorted[pos] = (u16)src[e];
    }
}

// ---------------- single-pass gather aggregation: one wave per node ------
// lane roles: l<32: ft cols [4l..4l+3] (head=l>>3); 32<=l<48: y cols
// [4cg..4cg+3] for head=(l-32)>>2, cg=(l-32)&3; l>=48 idle.
__global__ __launch_bounds__(256) void k_agg(
    const char* __restrict__ comb, const float* __restrict__ bias,
    const int* __restrict__ row_off, const u16* __restrict__ ss,
    float* __restrict__ rst, float* __restrict__ yp, int N) {
    int w = (int)((blockIdx.x * (size_t)blockDim.x + threadIdx.x) >> 6);
    int lane = threadIdx.x & 63;
    if (w >= N) return;

    bool is_ft = lane < 32;
    bool is_y = lane >= 32 && lane < 48;
    int cg = (lane - 32) & 3;
    int head = is_ft ? (lane >> 3) : (is_y ? ((lane - 32) >> 2) : 0);
    int off8 = is_ft ? lane : (is_y ? (32 + cg) : 0);   // dword2 index in row
    int elo = 288 + 8 * (head >> 1);                    // el pair byte offset

    const char* roww = comb + (size_t)w * ROWB;
    float2 erp = *(const float2*)(roww + 304 + 8 * (head >> 1));
    float er_l = (head & 1) ? erp.y : erp.x;

    int beg = row_off[w], end = row_off[w + 1];
    float4 acc = make_float4(0.f, 0.f, 0.f, 0.f);
    float ssum = 0.f;

#define ROWLD(s, v, ep)                                                     \
    {                                                                       \
        const char* rb = comb + (size_t)(s)*ROWB;                           \
        v = *(const uint2*)(rb + 8 * off8);                                 \
        ep = *(const float2*)(rb + elo);                                    \
    }
#define COMPUTE(v, ep)                                                      \
    {                                                                       \
        float el_h = (head & 1) ? ep.y : ep.x;                              \
        float e = el_h + er_l;                                              \
        e = fmaxf(e, NEG_SLOPE * e);                                        \
        float ee = __expf(e);                                               \
        ssum += ee;                                                         \
        float f0 = __uint_as_float(v.x << 16);                              \
        float f1 = __uint_as_float(v.x & 0xffff0000u);                      \
        float f2 = __uint_as_float(v.y << 16);                              \
        float f3 = __uint_as_float(v.y & 0xffff0000u);                      \
        acc.x = fmaf(ee, f0, acc.x);                                        \
        acc.y = fmaf(ee, f1, acc.y);                                        \
        acc.z = fmaf(ee, f2, acc.z);                                        \
        acc.w = fmaf(ee, f3, acc.w);                                        \
    }

    if (beg < end) {
        int im = end - 1;
        int s0 = ss[beg];
        int s1 = ss[min(beg + 1, im)];
        uint2 v0, v1;
        float2 e0, e1;
        ROWLD(s0, v0, e0);
        ROWLD(s1, v1, e1);
        for (int i = beg; i < end; ++i) {
            int s2 = ss[min(i + 2, im)];
            uint2 v2;
            float2 e2;
            ROWLD(s2, v2, e2);
            COMPUTE(v0, e0);
            v0 = v1; e0 = e1;
            v1 = v2; e1 = e2;
        }
    }
#undef ROWLD
#undef COMPUTE

    float inv = 1.f / fmaxf(ssum, 1e-9f);
    acc.x *= inv; acc.y *= inv; acc.z *= inv; acc.w *= inv;

    if (is_ft) {
        float4 b4 = *(const float4*)(bias + 4 * lane);
        acc.x += b4.x; acc.y += b4.y; acc.z += b4.z; acc.w += b4.w;
        *(float4*)(rst + (size_t)w * 128 + 4 * lane) = acc;
    } else if (is_y) {
        *(float4*)(yp + (size_t)w * 64 + 16 * head + 4 * cg) = acc;
    }
}

extern "C" void kernel_launch(void* const* d_in, const int* in_sizes, int n_in,
                              void* d_out, int out_size, void* d_ws, size_t ws_size,
                              hipStream_t stream) {
    const float* feat   = (const float*)d_in[0];
    const float* y      = (const float*)d_in[1];
    const float* fc_w   = (const float*)d_in[2];
    const float* attn_l = (const float*)d_in[3];
    const float* attn_r = (const float*)d_in[4];
    const float* bias   = (const float*)d_in[5];
    const int*   src    = (const int*)d_in[6];
    const int*   dst    = (const int*)d_in[7];

    const int N = in_sizes[0] / 128;  // FIN = 128
    const int E = in_sizes[6];

    char* comb = (char*)d_ws;                        // N * 320 bytes
    int* cnt = (int*)(comb + (size_t)N * ROWB);      // N
    int* row_off = cnt + N;                          // N+1
    int* cursor = row_off + (N + 1);                 // N
    u16* src_sorted = (u16*)(cursor + N);            // E

    float* rst = (float*)d_out;                      // N*128
    float* yp = rst + (size_t)N * 128;               // N*64

    (void)hipMemsetAsync(cnt, 0, (size_t)N * sizeof(int), stream);

    const int projB = (N + 15) / 16;
    const int histB = 1024;
    const int scatB = 1024;

    k_proj<<<dim3(projB + histB), dim3(256), 0, stream>>>(
        feat, fc_w, y, attn_l, attn_r, comb, dst, cnt, N, E, projB, histB * 256);
    k_scan<<<dim3(1), dim3(1024), 0, stream>>>(cnt, row_off, cursor, N);
    k_scatter<<<dim3(scatB), dim3(256), 0, stream>>>(
        src, dst, cursor, src_sorted, E, scatB * 256);
    k_agg<<<dim3(((size_t)N * 64 + 255) / 256), dim3(256), 0, stream>>>(
        comb, bias, row_off, src_sorted, rst, yp, N);
}

// Round 5
// 212.282 us; speedup vs baseline: 1.8181x; 1.7063x over previous
//
#include <hip/hip_runtime.h>
#include <hip/hip_bf16.h>

#define NEG_SLOPE 0.2f
#define ROWB 320  // bytes per node row: ft bf16[128] | y bf16[16] | el f32[4] | er f32[4]

typedef unsigned short u16;
typedef unsigned int u32;

__device__ __forceinline__ u16 f32_to_bf16(float x) {
    u32 u = __float_as_uint(x);
    u32 r = u + 0x7fffu + ((u >> 16) & 1u);  // round-to-nearest-even
    return (u16)(r >> 16);
}

// ---------------- k1: projection + el/er + bf16 pack + y cast (+ hist) ----
__global__ __launch_bounds__(256) void k_proj(
    const float* __restrict__ feat, const float* __restrict__ fc_w,
    const float* __restrict__ y, const float* __restrict__ attn_l,
    const float* __restrict__ attn_r, char* __restrict__ comb,
    const int* __restrict__ dst, int* __restrict__ cnt,
    int N, int E, int projB, int histThreads) {
    __shared__ float fl[16 * 128];
    int t = threadIdx.x;
    if ((int)blockIdx.x >= projB) {
        int tid = (blockIdx.x - projB) * 256 + t;
        for (int e = tid; e < E; e += histThreads) atomicAdd(&cnt[dst[e]], 1);
        return;
    }
    int n0 = blockIdx.x * 16;
#pragma unroll
    for (int j = 0; j < 8; ++j) {
        int idx = j * 256 + t;
        int r = idx >> 7, c = idx & 127;
        int n = n0 + r;
        fl[idx] = (n < N) ? feat[(size_t)n * 128 + c] : 0.f;
    }
    {
        int jj = t >> 4, col = t & 15;
        int n = n0 + jj;
        if (n < N) {
            float yv = y[(size_t)n * 16 + col];
            *(u16*)(comb + (size_t)n * ROWB + 256 + 2 * col) = f32_to_bf16(yv);
        }
    }
    __syncthreads();

    int c = t & 63;
    int g = t >> 6;
    float alv0 = attn_l[c], alv1 = attn_l[64 + c];
    float arv0 = attn_r[c], arv1 = attn_r[64 + c];

    float acc[4][2];
#pragma unroll
    for (int j = 0; j < 4; ++j) acc[j][0] = acc[j][1] = 0.f;

    const float* fb = fl + g * 4 * 128;
    for (int k = 0; k < 128; k += 4) {
        float wa0 = fc_w[(size_t)(k + 0) * 128 + c];
        float wb0 = fc_w[(size_t)(k + 0) * 128 + c + 64];
        float wa1 = fc_w[(size_t)(k + 1) * 128 + c];
        float wb1 = fc_w[(size_t)(k + 1) * 128 + c + 64];
        float wa2 = fc_w[(size_t)(k + 2) * 128 + c];
        float wb2 = fc_w[(size_t)(k + 2) * 128 + c + 64];
        float wa3 = fc_w[(size_t)(k + 3) * 128 + c];
        float wb3 = fc_w[(size_t)(k + 3) * 128 + c + 64];
#pragma unroll
        for (int j = 0; j < 4; ++j) {
            float4 f = *(const float4*)(fb + j * 128 + k);
            acc[j][0] = fmaf(f.x, wa0, acc[j][0]);
            acc[j][1] = fmaf(f.x, wb0, acc[j][1]);
            acc[j][0] = fmaf(f.y, wa1, acc[j][0]);
            acc[j][1] = fmaf(f.y, wb1, acc[j][1]);
            acc[j][0] = fmaf(f.z, wa2, acc[j][0]);
            acc[j][1] = fmaf(f.z, wb2, acc[j][1]);
            acc[j][0] = fmaf(f.w, wa3, acc[j][0]);
            acc[j][1] = fmaf(f.w, wb3, acc[j][1]);
        }
    }

#pragma unroll
    for (int j = 0; j < 4; ++j) {
        int n = n0 + g * 4 + j;
        if (n >= N) break;
        char* row = comb + (size_t)n * ROWB;
        *(u16*)(row + 2 * c) = f32_to_bf16(acc[j][0]);
        *(u16*)(row + 2 * (c + 64)) = f32_to_bf16(acc[j][1]);
        float p0 = acc[j][0] * alv0;
        float p1 = acc[j][1] * alv1;
        float q0 = acc[j][0] * arv0;
        float q1 = acc[j][1] * arv1;
#pragma unroll
        for (int off = 1; off < 32; off <<= 1) {
            p0 += __shfl_xor(p0, off);
            p1 += __shfl_xor(p1, off);
            q0 += __shfl_xor(q0, off);
            q1 += __shfl_xor(q1, off);
        }
        float* ep = (float*)(row + 288);
        if (c == 0) { ep[0] = p0; ep[2] = p1; ep[4] = q0; ep[6] = q1; }
        if (c == 32) { ep[1] = p0; ep[3] = p1; ep[5] = q0; ep[7] = q1; }
    }
}

// ---------------- hierarchical scan: 1024-elem blocks ---------------------
__global__ __launch_bounds__(256) void k_scan1(const int* __restrict__ cnt,
                                               int* __restrict__ bsum, int N) {
    int t = threadIdx.x;
    int i = blockIdx.x * 1024 + t * 4;
    int s = 0;
    if (i + 4 <= N) {
        int4 v = *(const int4*)(cnt + i);
        s = v.x + v.y + v.z + v.w;
    } else {
        for (int k = 0; k < 4; ++k)
            if (i + k < N) s += cnt[i + k];
    }
#pragma unroll
    for (int off = 1; off < 64; off <<= 1) s += __shfl_xor(s, off);
    __shared__ int ws[4];
    int lane = t & 63, wv = t >> 6;
    if (lane == 0) ws[wv] = s;
    __syncthreads();
    if (t == 0) bsum[blockIdx.x] = ws[0] + ws[1] + ws[2] + ws[3];
}

__global__ void k_scan2(const int* __restrict__ bsum, int* __restrict__ boff,
                        int* __restrict__ row_off, int nb, int N) {
    int t = threadIdx.x;
    if (nb > 64) {
        if (t == 0) {
            int r = 0;
            for (int i = 0; i < nb; ++i) { boff[i] = r; r += bsum[i]; }
            row_off[N] = r;
        }
        return;
    }
    int v = (t < nb) ? bsum[t] : 0;
    int incl = v;
#pragma unroll
    for (int off = 1; off < 64; off <<= 1) {
        int u = __shfl_up(incl, off);
        if (t >= off) incl += u;
    }
    if (t < nb) boff[t] = incl - v;
    if (t == nb - 1) row_off[N] = incl;
}

__global__ __launch_bounds__(256) void k_scan3(const int* __restrict__ cnt,
                                               const int* __restrict__ boff,
                                               int* __restrict__ row_off,
                                               int* __restrict__ cursor, int N) {
    int t = threadIdx.x;
    int i = blockIdx.x * 1024 + t * 4;
    int4 v = make_int4(0, 0, 0, 0);
    if (i + 4 <= N) {
        v = *(const int4*)(cnt + i);
    } else {
        if (i < N) v.x = cnt[i];
        if (i + 1 < N) v.y = cnt[i + 1];
        if (i + 2 < N) v.z = cnt[i + 2];
        if (i + 3 < N) v.w = cnt[i + 3];
    }
    int s = v.x + v.y + v.z + v.w;
    int lane = t & 63, wv = t >> 6;
    int incl = s;
#pragma unroll
    for (int off = 1; off < 64; off <<= 1) {
        int u = __shfl_up(incl, off);
        if (lane >= off) incl += u;
    }
    __shared__ int wsum[4];
    if (lane == 63) wsum[wv] = incl;
    __syncthreads();
    int wo = boff[blockIdx.x];
    for (int k = 0; k < wv; ++k) wo += wsum[k];
    int4 o;
    o.x = wo + incl - s;
    o.y = o.x + v.x;
    o.z = o.y + v.y;
    o.w = o.z + v.z;
    if (i + 4 <= N) {
        *(int4*)(row_off + i) = o;
        *(int4*)(cursor + i) = o;
    } else {
        if (i < N) { row_off[i] = o.x; cursor[i] = o.x; }
        if (i + 1 < N) { row_off[i + 1] = o.y; cursor[i + 1] = o.y; }
        if (i + 2 < N) { row_off[i + 2] = o.z; cursor[i + 2] = o.z; }
        if (i + 3 < N) { row_off[i + 3] = o.w; cursor[i + 3] = o.w; }
    }
}

// ---------------- scatter edge ids (u16) into CSR order ------------------
__global__ void k_scatter(const int* __restrict__ src, const int* __restrict__ dst,
                          int* __restrict__ cursor, u16* __restrict__ sst, int E) {
    int i = (blockIdx.x * 256 + threadIdx.x) * 4;
    if (i + 4 <= E) {
        int4 d = *(const int4*)(dst + i);
        int4 s = *(const int4*)(src + i);
        sst[atomicAdd(&cursor[d.x], 1)] = (u16)s.x;
        sst[atomicAdd(&cursor[d.y], 1)] = (u16)s.y;
        sst[atomicAdd(&cursor[d.z], 1)] = (u16)s.z;
        sst[atomicAdd(&cursor[d.w], 1)] = (u16)s.w;
    } else {
        for (int k = 0; k < 4 && i + k < E; ++k) {
            int p = atomicAdd(&cursor[dst[i + k]], 1);
            sst[p] = (u16)src[i + k];
        }
    }
}

// ---------------- gather aggregation: one wave per node, pipelined -------
__global__ __launch_bounds__(256) void k_agg(
    const char* __restrict__ comb, const float* __restrict__ bias,
    const int* __restrict__ row_off, const u16* __restrict__ ss,
    float* __restrict__ rst, float* __restrict__ yp, int N) {
    int w = (int)((blockIdx.x * (size_t)blockDim.x + threadIdx.x) >> 6);
    int lane = threadIdx.x & 63;
    if (w >= N) return;

    bool is_ft = lane < 32;
    int cg = (lane - 32) & 3;
    int head = (is_ft ? (lane >> 3) : ((lane - 32) >> 2)) & 3;
    int off8 = is_ft ? lane : (32 + cg);
    int elo = 288 + 8 * (head >> 1);
    bool ehi = (head & 1) != 0;

    const char* roww = comb + (size_t)w * ROWB;
    float2 erp = *(const float2*)(roww + 304 + 8 * (head >> 1));
    float er_l = ehi ? erp.y : erp.x;

    int beg = row_off[w], end = row_off[w + 1];
    float4 acc = make_float4(0.f, 0.f, 0.f, 0.f);
    float ssum = 0.f;

#define LOADE(idx, V, EP)                                       \
    {                                                           \
        int ii_ = min((idx), cl - 1);                           \
        int s_ = __builtin_amdgcn_readlane(my_s, ii_);          \
        const char* rb_ = comb + (size_t)s_ * ROWB;             \
        V = *(const uint2*)(rb_ + 8 * off8);                    \
        EP = *(const float2*)(rb_ + elo);                       \
    }
#define COMPE(idx, V, EP)                                       \
    {                                                           \
        float el_ = ehi ? EP.y : EP.x;                          \
        float e_ = el_ + er_l;                                  \
        e_ = fmaxf(e_, NEG_SLOPE * e_);                         \
        float ee_ = __expf(e_);                                 \
        ee_ = ((idx) < cl) ? ee_ : 0.f;                         \
        ssum += ee_;                                            \
        acc.x = fmaf(ee_, __uint_as_float(V.x << 16), acc.x);   \
        acc.y = fmaf(ee_, __uint_as_float(V.x & 0xffff0000u), acc.y); \
        acc.z = fmaf(ee_, __uint_as_float(V.y << 16), acc.z);   \
        acc.w = fmaf(ee_, __uint_as_float(V.y & 0xffff0000u), acc.w); \
    }
#define LOADG(qq, V0, V1, V2, V3, E0, E1, E2, E3)               \
    {                                                           \
        LOADE(4 * (qq) + 0, V0, E0);                            \
        LOADE(4 * (qq) + 1, V1, E1);                            \
        LOADE(4 * (qq) + 2, V2, E2);                            \
        LOADE(4 * (qq) + 3, V3, E3);                            \
    }
#define COMPG(qq, V0, V1, V2, V3, E0, E1, E2, E3)               \
    {                                                           \
        COMPE(4 * (qq) + 0, V0, E0);                            \
        COMPE(4 * (qq) + 1, V1, E1);                            \
        COMPE(4 * (qq) + 2, V2, E2);                            \
        COMPE(4 * (qq) + 3, V3, E3);                            \
    }

    for (int base = beg; base < end; base += 64) {
        int cl = min(64, end - base);
        int my_s = (int)ss[base + min(lane, cl - 1)];
        int nq = (cl + 3) >> 2;

        uint2 va0, va1, va2, va3, vb0, vb1, vb2, vb3;
        float2 ea0, ea1, ea2, ea3, eb0, eb1, eb2, eb3;

        LOADG(0, va0, va1, va2, va3, ea0, ea1, ea2, ea3);
        int q = 0;
        for (; q + 2 <= nq; q += 2) {
            LOADG(q + 1, vb0, vb1, vb2, vb3, eb0, eb1, eb2, eb3);
            COMPG(q, va0, va1, va2, va3, ea0, ea1, ea2, ea3);
            LOADG(q + 2, va0, va1, va2, va3, ea0, ea1, ea2, ea3);
            COMPG(q + 1, vb0, vb1, vb2, vb3, eb0, eb1, eb2, eb3);
        }
        if (q < nq) {
            COMPG(q, va0, va1, va2, va3, ea0, ea1, ea2, ea3);
        }
    }
#undef LOADE
#undef COMPE
#undef LOADG
#undef COMPG

    float inv = 1.f / fmaxf(ssum, 1e-9f);
    acc.x *= inv; acc.y *= inv; acc.z *= inv; acc.w *= inv;

    if (is_ft) {
        float4 b4 = *(const float4*)(bias + 4 * lane);
        acc.x += b4.x; acc.y += b4.y; acc.z += b4.z; acc.w += b4.w;
        *(float4*)(rst + (size_t)w * 128 + 4 * lane) = acc;
    } else if (lane < 48) {
        *(float4*)(yp + (size_t)w * 64 + 16 * head + 4 * cg) = acc;
    }
}

extern "C" void kernel_launch(void* const* d_in, const int* in_sizes, int n_in,
                              void* d_out, int out_size, void* d_ws, size_t ws_size,
                              hipStream_t stream) {
    const float* feat   = (const float*)d_in[0];
    const float* y      = (const float*)d_in[1];
    const float* fc_w   = (const float*)d_in[2];
    const float* attn_l = (const float*)d_in[3];
    const float* attn_r = (const float*)d_in[4];
    const float* bias   = (const float*)d_in[5];
    const int*   src    = (const int*)d_in[6];
    const int*   dst    = (const int*)d_in[7];

    const int N = in_sizes[0] / 128;  // FIN = 128
    const int E = in_sizes[6];

    char* comb = (char*)d_ws;                        // N * 320 B (16B aligned)
    int* cnt = (int*)(comb + (size_t)N * ROWB);      // N
    int* cursor = cnt + N;                           // N   (16B aligned)
    int* row_off = cursor + N;                       // N+1 (16B aligned)
    u16* src_sorted = (u16*)(row_off + N + 1);       // E
    int* bsum = (int*)(src_sorted + ((E + 1) & ~1)); // nb
    int* boff = bsum + 256;                          // nb

    float* rst = (float*)d_out;                      // N*128
    float* yp = rst + (size_t)N * 128;               // N*64

    (void)hipMemsetAsync(cnt, 0, (size_t)N * sizeof(int), stream);

    const int projB = (N + 15) / 16;
    const int histB = 1024;
    const int nb = (N + 1023) / 1024;

    k_proj<<<dim3(projB + histB), dim3(256), 0, stream>>>(
        feat, fc_w, y, attn_l, attn_r, comb, dst, cnt, N, E, projB, histB * 256);
    k_scan1<<<dim3(nb), dim3(256), 0, stream>>>(cnt, bsum, N);
    k_scan2<<<dim3(1), dim3(64), 0, stream>>>(bsum, boff, row_off, nb, N);
    k_scan3<<<dim3(nb), dim3(256), 0, stream>>>(cnt, boff, row_off, cursor, N);
    k_scatter<<<dim3((E + 1023) / 1024), dim3(256), 0, stream>>>(
        src, dst, cursor, src_sorted, E);
    k_agg<<<dim3(((size_t)N * 64 + 255) / 256), dim3(256), 0, stream>>>(
        comb, bias, row_off, src_sorted, rst, yp, N);
}